// Round 17
// baseline (45.116 us; speedup 1.0000x reference)
//
#include <hip/hip_runtime.h>
#include <hip/hip_bf16.h>
#include <math.h>

#define BB 4
#define HH 128
#define WW 128
#define CIN 64
#define COUT 64
#define KK 9
#define OMC 27
#define NPIX (BB * HH * WW)

typedef __attribute__((ext_vector_type(8))) short bf16x8;
typedef __attribute__((ext_vector_type(4))) float f32x4;

static __device__ __forceinline__ unsigned int pkcvt(float a, float b) {
    __hip_bfloat162 h = __float22bfloat162_rn(make_float2(a, b));
    return *reinterpret_cast<unsigned int*>(&h);
}

// ---------------------------------------------------------------------------
// Kernel 0: one-shot weight transforms.
//  tid < 4608:  wmain f32 [576 k][64 n] -> wb bf16 B-frags  [18 ks][4 nf][64]
//  else      :  wofs  f32 [9 t][64 c][27 j] -> wf bf16 B-frags [18 ks][2 nf][64]
//               (ks = t*2 + ch-half, j padded to 32 with zeros)
// ---------------------------------------------------------------------------
__global__ __launch_bounds__(64) void weight_transform(
    const float* __restrict__ wmain, const float* __restrict__ wofs,
    uint4* __restrict__ wb, uint4* __restrict__ wf)
{
    const int tg = blockIdx.x * 64 + threadIdx.x;
    if (tg < 4608) {
        const int lane = tg & 63;
        const int nf   = (tg >> 6) & 3;
        const int ks   = tg >> 8;
        const int k0   = ks * 32 + ((lane >> 4) * 8);
        const int n    = nf * 16 + (lane & 15);
        uint4 q;
        q.x = pkcvt(wmain[(size_t)(k0 + 0) * COUT + n], wmain[(size_t)(k0 + 1) * COUT + n]);
        q.y = pkcvt(wmain[(size_t)(k0 + 2) * COUT + n], wmain[(size_t)(k0 + 3) * COUT + n]);
        q.z = pkcvt(wmain[(size_t)(k0 + 4) * COUT + n], wmain[(size_t)(k0 + 5) * COUT + n]);
        q.w = pkcvt(wmain[(size_t)(k0 + 6) * COUT + n], wmain[(size_t)(k0 + 7) * COUT + n]);
        wb[tg] = q;
    } else {
        const int idx  = tg - 4608;            // [0, 2304)
        const int lane = idx & 63;
        const int frag = idx >> 6;             // [0, 36) = ks*2 + nf
        const int nf   = frag & 1;
        const int ks   = frag >> 1;
        const int t    = ks >> 1;
        const int kw   = ks & 1;
        const int j    = nf * 16 + (lane & 15);
        const int c0   = kw * 32 + ((lane >> 4) * 8);
        uint4 q;
        if (j < OMC) {
            const float* wp = wofs + ((size_t)t * CIN + c0) * OMC + j;
            q.x = pkcvt(wp[0 * OMC], wp[1 * OMC]);
            q.y = pkcvt(wp[2 * OMC], wp[3 * OMC]);
            q.z = pkcvt(wp[4 * OMC], wp[5 * OMC]);
            q.w = pkcvt(wp[6 * OMC], wp[7 * OMC]);
        } else {
            q.x = q.y = q.z = q.w = 0u;
        }
        wf[frag * 64 + lane] = q;
    }
}

// ---------------------------------------------------------------------------
// FUSED kernel: offset-conv GEMM + deformable sampling + main MFMA.
// LDS OVERLAYS (barrier-separated lifetimes), total 24704 B:
//   [0,13056)      xs (ph0-1)  -> ent_w/ent_o (ph2-3, 9216) -> red (ph4, 8192)
//   [13056,16512)  om_s (ph1->2-3)
//   [16512,24704)  om_red (ph1 reduce, 4096) -> ts wave tiles (ph3, 4 x 2048)
// amdgpu_waves_per_eu(4,4): pins the scheduler's 128-VGPR budget so the
// gather pipeline keeps its live set (R15/R16 lesson).
// Phase 3 is now a 3-STAGE pipeline: ISSUE(t+2) || WRITE(t+1) || DOMFMA(t),
// with DOUBLE-BUFFERED per-wave tiles (buf = t&1).  This moves each tap's
// ds_write -> ds_read turn-around off the critical path (it was serialized
// inside every tap in R13-R16).  In-order DS pipe guarantees the buf-reuse
// hazard (read buf0@t before write buf0@t+2) is safe.
// ---------------------------------------------------------------------------
#define TMB 32   // pixels per block

__global__ __launch_bounds__(256)
__attribute__((amdgpu_waves_per_eu(4, 4)))
void dcn_fused(
    const float* __restrict__ x,
    const uint4* __restrict__ wb,
    const uint4* __restrict__ wf,
    const float* __restrict__ bias,
    const float* __restrict__ bofs,
    float* __restrict__ out)
{
    __shared__ char shm[13056 + 3456 + 8192];
    char*   xs    = shm;                             // phase 0-1
    float4* ent_w = (float4*)shm;                    // phase 2-3 (overlay xs)
    int4*   ent_o = (int4*)(shm + 4608);             // phase 2-3
    float*  om_s  = (float*)(shm + 13056);           // 32*27 f32
    char*   ts    = shm + 13056 + 3456;              // phase 3: 4 x 2048 (dbuf)
    f32x4*  om_red = (f32x4*)ts;                     // phase 1 reduce (overlay ts)
    f32x4*  red   = (f32x4*)shm;                     // phase 4 (overlay ent)

    const int tid  = threadIdx.x;
    const int lane = tid & 63;
    const int wv   = tid >> 6;
    const int pair = wv >> 1;
    const int kw   = wv & 1;
    const int bid  = ((blockIdx.x & 7) << 8) + (blockIdx.x >> 3);  // XCD chunk
    const int pix0 = bid * TMB;
    const int b    = pix0 >> 14;
    const int h    = (pix0 >> 7) & (HH - 1);
    const int w0   = pix0 & (WW - 1);
    const float* xb = x + (size_t)b * HH * WW * CIN;

    // ---- phase 0: stage x tile [3][34][64] bf16, swizzled ----
    #pragma unroll
    for (int it = 0; it < 4; ++it) {
        const int idx = it * 256 + tid;
        if (idx < 816) {
            const int c8   = idx & 7;
            const int rest = idx >> 3;          // [0,102)
            const int ty   = rest / 34;
            const int wi   = rest - ty * 34;
            const int hy   = h - 1 + ty;
            const int wcol = w0 - 1 + wi;
            uint4 q;
            if ((unsigned)hy < (unsigned)HH && (unsigned)wcol < (unsigned)WW) {
                const float* p = xb + ((size_t)hy * WW + wcol) * CIN + c8 * 8;
                const float4 a0 = *(const float4*)p;
                const float4 a1 = *(const float4*)(p + 4);
                q.x = pkcvt(a0.x, a0.y);
                q.y = pkcvt(a0.z, a0.w);
                q.z = pkcvt(a1.x, a1.y);
                q.w = pkcvt(a1.z, a1.w);
            } else {
                q.x = q.y = q.z = q.w = 0u;
            }
            const int off = ((ty * 34 + wi) * 128 + c8 * 16) ^ ((wi & 7) << 4);
            *(uint4*)(xs + off) = q;
        }
    }
    __syncthreads();

    // ---- phase 1: om GEMM ----
    f32x4 accm[2] = {};
    #pragma unroll
    for (int t = 0; t < KK; ++t) {
        const int ty = t / 3, tx = t % 3;
        const int wi = pair * 16 + (lane & 15) + tx;
        const int aoff = ((ty * 34 + wi) * 128 + kw * 64 + ((lane >> 4) * 16))
                         ^ ((wi & 7) << 4);
        const bf16x8 a = *(const bf16x8*)(xs + aoff);
        const uint4* wf0 = wf + ((t * 2 + kw) * 2) * 64 + lane;
        const bf16x8 b0 = *(const bf16x8*)(wf0);
        const bf16x8 b1 = *(const bf16x8*)(wf0 + 64);
        accm[0] = __builtin_amdgcn_mfma_f32_16x16x32_bf16(a, b0, accm[0], 0, 0, 0);
        accm[1] = __builtin_amdgcn_mfma_f32_16x16x32_bf16(a, b1, accm[1], 0, 0, 0);
    }

    // pair-reduce om + epilogue -> om_s   (om_red lives in the ts region)
    if (kw == 1) {
        om_red[(pair * 2 + 0) * 64 + lane] = accm[0];
        om_red[(pair * 2 + 1) * 64 + lane] = accm[1];
    }
    __syncthreads();
    if (kw == 0) {
        #pragma unroll
        for (int nf = 0; nf < 2; ++nf) {
            const int j = nf * 16 + (lane & 15);
            if (j >= OMC) continue;
            const f32x4 o = om_red[(pair * 2 + nf) * 64 + lane];
            const float bb = bofs[j];
            const int m0 = pair * 16 + ((lane >> 4) * 4);
            #pragma unroll
            for (int r = 0; r < 4; ++r) {
                float val = accm[nf][r] + o[r] + bb;
                const int wpix = w0 + m0 + r;
                if (j < 18) {
                    const int t = j >> 1;
                    if ((j & 1) == 0) val += (float)(h - 1 + t / 3);     // abs py
                    else              val += (float)(wpix - 1 + t % 3);  // abs px
                } else {
                    val = 1.0f / (1.0f + __expf(-val));                  // sigmoid
                }
                om_s[(m0 + r) * OMC + j] = val;
            }
        }
    }
    __syncthreads();

    // ---- phase 2: entry precompute from om_s (ent overlays dead xs) ----
    for (int e = tid; e < 288; e += 256) {
        const int px = e / 9;
        const int t  = e - px * 9;
        const float py  = om_s[px * OMC + 2 * t];
        const float pxx = om_s[px * OMC + 2 * t + 1];
        const float mk  = om_s[px * OMC + 18 + t];

        const float fy = floorf(py), fx = floorf(pxx);
        const int y0 = (int)fy, x0 = (int)fx;
        const float wy1 = py - fy, wx1 = pxx - fx;
        const float wy0 = 1.0f - wy1, wx0 = 1.0f - wx1;
        const bool vy0 = (unsigned)y0 < (unsigned)HH;
        const bool vy1 = (unsigned)(y0 + 1) < (unsigned)HH;
        const bool vx0 = (unsigned)x0 < (unsigned)WW;
        const bool vx1 = (unsigned)(x0 + 1) < (unsigned)WW;
        float4 w4;
        w4.x = (vy0 && vx0) ? wy0 * wx0 * mk : 0.0f;
        w4.y = (vy0 && vx1) ? wy0 * wx1 * mk : 0.0f;
        w4.z = (vy1 && vx0) ? wy1 * wx0 * mk : 0.0f;
        w4.w = (vy1 && vx1) ? wy1 * wx1 * mk : 0.0f;
        const int yc0 = min(max(y0, 0), HH - 1);
        const int yc1 = min(max(y0 + 1, 0), HH - 1);
        const int xc0 = min(max(x0, 0), WW - 1);
        const int xc1 = min(max(x0 + 1, 0), WW - 1);
        int4 o4;
        o4.x = (yc0 * WW + xc0) * (CIN * 4);
        o4.y = (yc0 * WW + xc1) * (CIN * 4);
        o4.z = (yc1 * WW + xc0) * (CIN * 4);
        o4.w = (yc1 * WW + xc1) * (CIN * 4);
        ent_w[e] = w4;
        ent_o[e] = o4;
    }
    __syncthreads();

    // ---- phase 3: 3-stage pipeline (ISSUE || WRITE || DOMFMA, dbuf ts) ----
    char* tsw = ts + wv * 2048;
    const int plane = lane >> 3;
    const int ch0   = (lane & 7) * 4;
    const char* xc  = (const char*)xb + (size_t)(kw * 32 + ch0) * 4;
    const int e0b = pair * 144 + plane * 9;
    const int e1b = pair * 144 + (8 + plane) * 9;

    const int px0 = plane, px1 = 8 + plane;
    const int woff0 = px0 * 64 + (((lane & 7) * 8) ^ ((px0 & 3) << 4));
    const int woff1 = px1 * 64 + (((lane & 7) * 8) ^ ((px1 & 3) << 4));
    const int arow  = lane & 15;
    const int aoff  = arow * 64 + ((((lane >> 4) * 16)) ^ ((arow & 3) << 4));

    f32x4 acc[4] = {};

#define ISSUE(S, t) {                                                         \
        w0##S = ent_w[e0b + (t)];                                             \
        w1##S = ent_w[e1b + (t)];                                             \
        const int4 oa = ent_o[e0b + (t)];                                     \
        const int4 ob = ent_o[e1b + (t)];                                     \
        c00##S = *(const float4*)(xc + oa.x);                                 \
        c01##S = *(const float4*)(xc + oa.y);                                 \
        c02##S = *(const float4*)(xc + oa.z);                                 \
        c03##S = *(const float4*)(xc + oa.w);                                 \
        c10##S = *(const float4*)(xc + ob.x);                                 \
        c11##S = *(const float4*)(xc + ob.y);                                 \
        c12##S = *(const float4*)(xc + ob.z);                                 \
        c13##S = *(const float4*)(xc + ob.w);                                 \
    }

#define WRITE(S, t) {                                                         \
        const int bo = ((t) & 1) * 1024;                                      \
        {                                                                     \
            const float4 w4 = w0##S;                                          \
            const float s0 = w4.x*c00##S.x + w4.y*c01##S.x                    \
                           + w4.z*c02##S.x + w4.w*c03##S.x;                   \
            const float s1 = w4.x*c00##S.y + w4.y*c01##S.y                    \
                           + w4.z*c02##S.y + w4.w*c03##S.y;                   \
            const float s2 = w4.x*c00##S.z + w4.y*c01##S.z                    \
                           + w4.z*c02##S.z + w4.w*c03##S.z;                   \
            const float s3 = w4.x*c00##S.w + w4.y*c01##S.w                    \
                           + w4.z*c02##S.w + w4.w*c03##S.w;                   \
            uint2 pkd; pkd.x = pkcvt(s0, s1); pkd.y = pkcvt(s2, s3);          \
            *(uint2*)(tsw + bo + woff0) = pkd;                                \
        }                                                                     \
        {                                                                     \
            const float4 w4 = w1##S;                                          \
            const float s0 = w4.x*c10##S.x + w4.y*c11##S.x                    \
                           + w4.z*c12##S.x + w4.w*c13##S.x;                   \
            const float s1 = w4.x*c10##S.y + w4.y*c11##S.y                    \
                           + w4.z*c12##S.y + w4.w*c13##S.y;                   \
            const float s2 = w4.x*c10##S.z + w4.y*c11##S.z                    \
                           + w4.z*c12##S.z + w4.w*c13##S.z;                   \
            const float s3 = w4.x*c10##S.w + w4.y*c11##S.w                    \
                           + w4.z*c12##S.w + w4.w*c13##S.w;                   \
            uint2 pkd; pkd.x = pkcvt(s0, s1); pkd.y = pkcvt(s2, s3);          \
            *(uint2*)(tsw + bo + woff1) = pkd;                                \
        }                                                                     \
    }

#define DOMFMA(t) {                                                           \
        const bf16x8 a = *(const bf16x8*)(tsw + (((t) & 1) * 1024) + aoff);   \
        const uint4* wb0 = wb + ((t) * 2 + kw) * 4 * 64 + lane;               \
        const bf16x8 b0 = *(const bf16x8*)(wb0 + 0 * 64);                     \
        const bf16x8 b1 = *(const bf16x8*)(wb0 + 1 * 64);                     \
        const bf16x8 b2 = *(const bf16x8*)(wb0 + 2 * 64);                     \
        const bf16x8 b3 = *(const bf16x8*)(wb0 + 3 * 64);                     \
        acc[0] = __builtin_amdgcn_mfma_f32_16x16x32_bf16(a, b0, acc[0], 0, 0, 0); \
        acc[1] = __builtin_amdgcn_mfma_f32_16x16x32_bf16(a, b1, acc[1], 0, 0, 0); \
        acc[2] = __builtin_amdgcn_mfma_f32_16x16x32_bf16(a, b2, acc[2], 0, 0, 0); \
        acc[3] = __builtin_amdgcn_mfma_f32_16x16x32_bf16(a, b3, acc[3], 0, 0, 0); \
    }

    float4 w0A, w1A, c00A, c01A, c02A, c03A, c10A, c11A, c12A, c13A;
    float4 w0B, w1B, c00B, c01B, c02B, c03B, c10B, c11B, c12B, c13B;

    ISSUE(A, 0)
    ISSUE(B, 1) WRITE(A, 0)
    ISSUE(A, 2) WRITE(B, 1) DOMFMA(0)
    ISSUE(B, 3) WRITE(A, 2) DOMFMA(1)
    ISSUE(A, 4) WRITE(B, 3) DOMFMA(2)
    ISSUE(B, 5) WRITE(A, 4) DOMFMA(3)
    ISSUE(A, 6) WRITE(B, 5) DOMFMA(4)
    ISSUE(B, 7) WRITE(A, 6) DOMFMA(5)
    ISSUE(A, 8) WRITE(B, 7) DOMFMA(6)
                WRITE(A, 8) DOMFMA(7)
                            DOMFMA(8)

#undef ISSUE
#undef WRITE
#undef DOMFMA

    // ---- phase 4: pair reduction (red overlays dead ent area) ----
    __syncthreads();
    if (kw == 1) {
        #pragma unroll
        for (int nf = 0; nf < 4; ++nf) red[(pair * 4 + nf) * 64 + lane] = acc[nf];
    }
    __syncthreads();
    if (kw == 0) {
        #pragma unroll
        for (int nf = 0; nf < 4; ++nf) {
            const f32x4 o = red[(pair * 4 + nf) * 64 + lane];
            const int n  = nf * 16 + (lane & 15);
            const float bs = bias[n];
            const int m0 = pair * 16 + ((lane >> 4) * 4);
            #pragma unroll
            for (int r = 0; r < 4; ++r) {
                out[(size_t)(pix0 + m0 + r) * COUT + n] = acc[nf][r] + o[r] + bs;
            }
        }
    }
}

extern "C" void kernel_launch(void* const* d_in, const int* in_sizes, int n_in,
                              void* d_out, int out_size, void* d_ws, size_t ws_size,
                              hipStream_t stream)
{
    const float* x     = (const float*)d_in[0];
    const float* wmain = (const float*)d_in[1];
    const float* bias  = (const float*)d_in[2];
    const float* wofs  = (const float*)d_in[3];
    const float* bofs  = (const float*)d_in[4];
    float* out = (float*)d_out;
    uint4* wb  = (uint4*)d_ws;                          // 73728 B
    uint4* wf  = (uint4*)((char*)d_ws + 73728);         // 36864 B

    weight_transform<<<108, 64, 0, stream>>>(wmain, wofs, wb, wf);
    dcn_fused<<<NPIX / TMB, 256, 0, stream>>>(x, wb, wf, bias, bofs, out);
}

// Round 18
// 43.852 us; speedup vs baseline: 1.0288x; 1.0288x over previous
//
#include <hip/hip_runtime.h>
#include <hip/hip_bf16.h>
#include <math.h>

#define BB 4
#define HH 128
#define WW 128
#define CIN 64
#define COUT 64
#define KK 9
#define OMC 27
#define NPIX (BB * HH * WW)

typedef __attribute__((ext_vector_type(8))) short bf16x8;
typedef __attribute__((ext_vector_type(4))) float f32x4;

static __device__ __forceinline__ unsigned int pkcvt(float a, float b) {
    __hip_bfloat162 h = __float22bfloat162_rn(make_float2(a, b));
    return *reinterpret_cast<unsigned int*>(&h);
}

// ---------------------------------------------------------------------------
// Kernel 0: one-shot weight transforms.
//  tid < 4608:  wmain f32 [576 k][64 n] -> wb bf16 B-frags  [18 ks][4 nf][64]
//  else      :  wofs  f32 [9 t][64 c][27 j] -> wf bf16 B-frags [18 ks][2 nf][64]
//               (ks = t*2 + ch-half, j padded to 32 with zeros)
// ---------------------------------------------------------------------------
__global__ __launch_bounds__(64) void weight_transform(
    const float* __restrict__ wmain, const float* __restrict__ wofs,
    uint4* __restrict__ wb, uint4* __restrict__ wf)
{
    const int tg = blockIdx.x * 64 + threadIdx.x;
    if (tg < 4608) {
        const int lane = tg & 63;
        const int nf   = (tg >> 6) & 3;
        const int ks   = tg >> 8;
        const int k0   = ks * 32 + ((lane >> 4) * 8);
        const int n    = nf * 16 + (lane & 15);
        uint4 q;
        q.x = pkcvt(wmain[(size_t)(k0 + 0) * COUT + n], wmain[(size_t)(k0 + 1) * COUT + n]);
        q.y = pkcvt(wmain[(size_t)(k0 + 2) * COUT + n], wmain[(size_t)(k0 + 3) * COUT + n]);
        q.z = pkcvt(wmain[(size_t)(k0 + 4) * COUT + n], wmain[(size_t)(k0 + 5) * COUT + n]);
        q.w = pkcvt(wmain[(size_t)(k0 + 6) * COUT + n], wmain[(size_t)(k0 + 7) * COUT + n]);
        wb[tg] = q;
    } else {
        const int idx  = tg - 4608;            // [0, 2304)
        const int lane = idx & 63;
        const int frag = idx >> 6;             // [0, 36) = ks*2 + nf
        const int nf   = frag & 1;
        const int ks   = frag >> 1;
        const int t    = ks >> 1;
        const int kw   = ks & 1;
        const int j    = nf * 16 + (lane & 15);
        const int c0   = kw * 32 + ((lane >> 4) * 8);
        uint4 q;
        if (j < OMC) {
            const float* wp = wofs + ((size_t)t * CIN + c0) * OMC + j;
            q.x = pkcvt(wp[0 * OMC], wp[1 * OMC]);
            q.y = pkcvt(wp[2 * OMC], wp[3 * OMC]);
            q.z = pkcvt(wp[4 * OMC], wp[5 * OMC]);
            q.w = pkcvt(wp[6 * OMC], wp[7 * OMC]);
        } else {
            q.x = q.y = q.z = q.w = 0u;
        }
        wf[frag * 64 + lane] = q;
    }
}

// ---------------------------------------------------------------------------
// FUSED kernel: offset-conv GEMM + deformable sampling + main MFMA.
// LDS OVERLAYS (barrier-separated lifetimes), total 24704 B:
//   [0,13056)      xs (ph0-1)  -> ent_w/ent_o (ph2-3, 9216) -> red (ph4, 8192)
//   [13056,16512)  om_s (ph1->2-3)
//   [16512,24704)  om_red (ph1 reduce, 4096) -> ts wave tiles (ph3, 4 x 2048)
// amdgpu_waves_per_eu(4,6): target ceiling 6 waves/EU -> VGPR budget 85.
// Current pipeline needs 64, so codegen should be UNCHANGED (unlike R15's
// target-7/budget-73 which compressed to 40), while hardware residency can
// rise from 4 to 6 blocks/CU (LDS 25088*6 = 147KB <= 160KB).
// Phase 3: 3-stage pipeline ISSUE(t+2) || WRITE(t+1) || DOMFMA(t), dbuf ts.
// ---------------------------------------------------------------------------
#define TMB 32   // pixels per block

__global__ __launch_bounds__(256)
__attribute__((amdgpu_waves_per_eu(4, 6)))
void dcn_fused(
    const float* __restrict__ x,
    const uint4* __restrict__ wb,
    const uint4* __restrict__ wf,
    const float* __restrict__ bias,
    const float* __restrict__ bofs,
    float* __restrict__ out)
{
    __shared__ char shm[13056 + 3456 + 8192];
    char*   xs    = shm;                             // phase 0-1
    float4* ent_w = (float4*)shm;                    // phase 2-3 (overlay xs)
    int4*   ent_o = (int4*)(shm + 4608);             // phase 2-3
    float*  om_s  = (float*)(shm + 13056);           // 32*27 f32
    char*   ts    = shm + 13056 + 3456;              // phase 3: 4 x 2048 (dbuf)
    f32x4*  om_red = (f32x4*)ts;                     // phase 1 reduce (overlay ts)
    f32x4*  red   = (f32x4*)shm;                     // phase 4 (overlay ent)

    const int tid  = threadIdx.x;
    const int lane = tid & 63;
    const int wv   = tid >> 6;
    const int pair = wv >> 1;
    const int kw   = wv & 1;
    const int bid  = ((blockIdx.x & 7) << 8) + (blockIdx.x >> 3);  // XCD chunk
    const int pix0 = bid * TMB;
    const int b    = pix0 >> 14;
    const int h    = (pix0 >> 7) & (HH - 1);
    const int w0   = pix0 & (WW - 1);
    const float* xb = x + (size_t)b * HH * WW * CIN;

    // ---- phase 0: stage x tile [3][34][64] bf16, swizzled ----
    #pragma unroll
    for (int it = 0; it < 4; ++it) {
        const int idx = it * 256 + tid;
        if (idx < 816) {
            const int c8   = idx & 7;
            const int rest = idx >> 3;          // [0,102)
            const int ty   = rest / 34;
            const int wi   = rest - ty * 34;
            const int hy   = h - 1 + ty;
            const int wcol = w0 - 1 + wi;
            uint4 q;
            if ((unsigned)hy < (unsigned)HH && (unsigned)wcol < (unsigned)WW) {
                const float* p = xb + ((size_t)hy * WW + wcol) * CIN + c8 * 8;
                const float4 a0 = *(const float4*)p;
                const float4 a1 = *(const float4*)(p + 4);
                q.x = pkcvt(a0.x, a0.y);
                q.y = pkcvt(a0.z, a0.w);
                q.z = pkcvt(a1.x, a1.y);
                q.w = pkcvt(a1.z, a1.w);
            } else {
                q.x = q.y = q.z = q.w = 0u;
            }
            const int off = ((ty * 34 + wi) * 128 + c8 * 16) ^ ((wi & 7) << 4);
            *(uint4*)(xs + off) = q;
        }
    }
    __syncthreads();

    // ---- phase 1: om GEMM ----
    f32x4 accm[2] = {};
    #pragma unroll
    for (int t = 0; t < KK; ++t) {
        const int ty = t / 3, tx = t % 3;
        const int wi = pair * 16 + (lane & 15) + tx;
        const int aoff = ((ty * 34 + wi) * 128 + kw * 64 + ((lane >> 4) * 16))
                         ^ ((wi & 7) << 4);
        const bf16x8 a = *(const bf16x8*)(xs + aoff);
        const uint4* wf0 = wf + ((t * 2 + kw) * 2) * 64 + lane;
        const bf16x8 b0 = *(const bf16x8*)(wf0);
        const bf16x8 b1 = *(const bf16x8*)(wf0 + 64);
        accm[0] = __builtin_amdgcn_mfma_f32_16x16x32_bf16(a, b0, accm[0], 0, 0, 0);
        accm[1] = __builtin_amdgcn_mfma_f32_16x16x32_bf16(a, b1, accm[1], 0, 0, 0);
    }

    // pair-reduce om + epilogue -> om_s   (om_red lives in the ts region)
    if (kw == 1) {
        om_red[(pair * 2 + 0) * 64 + lane] = accm[0];
        om_red[(pair * 2 + 1) * 64 + lane] = accm[1];
    }
    __syncthreads();
    if (kw == 0) {
        #pragma unroll
        for (int nf = 0; nf < 2; ++nf) {
            const int j = nf * 16 + (lane & 15);
            if (j >= OMC) continue;
            const f32x4 o = om_red[(pair * 2 + nf) * 64 + lane];
            const float bb = bofs[j];
            const int m0 = pair * 16 + ((lane >> 4) * 4);
            #pragma unroll
            for (int r = 0; r < 4; ++r) {
                float val = accm[nf][r] + o[r] + bb;
                const int wpix = w0 + m0 + r;
                if (j < 18) {
                    const int t = j >> 1;
                    if ((j & 1) == 0) val += (float)(h - 1 + t / 3);     // abs py
                    else              val += (float)(wpix - 1 + t % 3);  // abs px
                } else {
                    val = 1.0f / (1.0f + __expf(-val));                  // sigmoid
                }
                om_s[(m0 + r) * OMC + j] = val;
            }
        }
    }
    __syncthreads();

    // ---- phase 2: entry precompute from om_s (ent overlays dead xs) ----
    for (int e = tid; e < 288; e += 256) {
        const int px = e / 9;
        const int t  = e - px * 9;
        const float py  = om_s[px * OMC + 2 * t];
        const float pxx = om_s[px * OMC + 2 * t + 1];
        const float mk  = om_s[px * OMC + 18 + t];

        const float fy = floorf(py), fx = floorf(pxx);
        const int y0 = (int)fy, x0 = (int)fx;
        const float wy1 = py - fy, wx1 = pxx - fx;
        const float wy0 = 1.0f - wy1, wx0 = 1.0f - wx1;
        const bool vy0 = (unsigned)y0 < (unsigned)HH;
        const bool vy1 = (unsigned)(y0 + 1) < (unsigned)HH;
        const bool vx0 = (unsigned)x0 < (unsigned)WW;
        const bool vx1 = (unsigned)(x0 + 1) < (unsigned)WW;
        float4 w4;
        w4.x = (vy0 && vx0) ? wy0 * wx0 * mk : 0.0f;
        w4.y = (vy0 && vx1) ? wy0 * wx1 * mk : 0.0f;
        w4.z = (vy1 && vx0) ? wy1 * wx0 * mk : 0.0f;
        w4.w = (vy1 && vx1) ? wy1 * wx1 * mk : 0.0f;
        const int yc0 = min(max(y0, 0), HH - 1);
        const int yc1 = min(max(y0 + 1, 0), HH - 1);
        const int xc0 = min(max(x0, 0), WW - 1);
        const int xc1 = min(max(x0 + 1, 0), WW - 1);
        int4 o4;
        o4.x = (yc0 * WW + xc0) * (CIN * 4);
        o4.y = (yc0 * WW + xc1) * (CIN * 4);
        o4.z = (yc1 * WW + xc0) * (CIN * 4);
        o4.w = (yc1 * WW + xc1) * (CIN * 4);
        ent_w[e] = w4;
        ent_o[e] = o4;
    }
    __syncthreads();

    // ---- phase 3: 3-stage pipeline (ISSUE || WRITE || DOMFMA, dbuf ts) ----
    char* tsw = ts + wv * 2048;
    const int plane = lane >> 3;
    const int ch0   = (lane & 7) * 4;
    const char* xc  = (const char*)xb + (size_t)(kw * 32 + ch0) * 4;
    const int e0b = pair * 144 + plane * 9;
    const int e1b = pair * 144 + (8 + plane) * 9;

    const int px0 = plane, px1 = 8 + plane;
    const int woff0 = px0 * 64 + (((lane & 7) * 8) ^ ((px0 & 3) << 4));
    const int woff1 = px1 * 64 + (((lane & 7) * 8) ^ ((px1 & 3) << 4));
    const int arow  = lane & 15;
    const int aoff  = arow * 64 + ((((lane >> 4) * 16)) ^ ((arow & 3) << 4));

    f32x4 acc[4] = {};

#define ISSUE(S, t) {                                                         \
        w0##S = ent_w[e0b + (t)];                                             \
        w1##S = ent_w[e1b + (t)];                                             \
        const int4 oa = ent_o[e0b + (t)];                                     \
        const int4 ob = ent_o[e1b + (t)];                                     \
        c00##S = *(const float4*)(xc + oa.x);                                 \
        c01##S = *(const float4*)(xc + oa.y);                                 \
        c02##S = *(const float4*)(xc + oa.z);                                 \
        c03##S = *(const float4*)(xc + oa.w);                                 \
        c10##S = *(const float4*)(xc + ob.x);                                 \
        c11##S = *(const float4*)(xc + ob.y);                                 \
        c12##S = *(const float4*)(xc + ob.z);                                 \
        c13##S = *(const float4*)(xc + ob.w);                                 \
    }

#define WRITE(S, t) {                                                         \
        const int bo = ((t) & 1) * 1024;                                      \
        {                                                                     \
            const float4 w4 = w0##S;                                          \
            const float s0 = w4.x*c00##S.x + w4.y*c01##S.x                    \
                           + w4.z*c02##S.x + w4.w*c03##S.x;                   \
            const float s1 = w4.x*c00##S.y + w4.y*c01##S.y                    \
                           + w4.z*c02##S.y + w4.w*c03##S.y;                   \
            const float s2 = w4.x*c00##S.z + w4.y*c01##S.z                    \
                           + w4.z*c02##S.z + w4.w*c03##S.z;                   \
            const float s3 = w4.x*c00##S.w + w4.y*c01##S.w                    \
                           + w4.z*c02##S.w + w4.w*c03##S.w;                   \
            uint2 pkd; pkd.x = pkcvt(s0, s1); pkd.y = pkcvt(s2, s3);          \
            *(uint2*)(tsw + bo + woff0) = pkd;                                \
        }                                                                     \
        {                                                                     \
            const float4 w4 = w1##S;                                          \
            const float s0 = w4.x*c10##S.x + w4.y*c11##S.x                    \
                           + w4.z*c12##S.x + w4.w*c13##S.x;                   \
            const float s1 = w4.x*c10##S.y + w4.y*c11##S.y                    \
                           + w4.z*c12##S.y + w4.w*c13##S.y;                   \
            const float s2 = w4.x*c10##S.z + w4.y*c11##S.z                    \
                           + w4.z*c12##S.z + w4.w*c13##S.z;                   \
            const float s3 = w4.x*c10##S.w + w4.y*c11##S.w                    \
                           + w4.z*c12##S.w + w4.w*c13##S.w;                   \
            uint2 pkd; pkd.x = pkcvt(s0, s1); pkd.y = pkcvt(s2, s3);          \
            *(uint2*)(tsw + bo + woff1) = pkd;                                \
        }                                                                     \
    }

#define DOMFMA(t) {                                                           \
        const bf16x8 a = *(const bf16x8*)(tsw + (((t) & 1) * 1024) + aoff);   \
        const uint4* wb0 = wb + ((t) * 2 + kw) * 4 * 64 + lane;               \
        const bf16x8 b0 = *(const bf16x8*)(wb0 + 0 * 64);                     \
        const bf16x8 b1 = *(const bf16x8*)(wb0 + 1 * 64);                     \
        const bf16x8 b2 = *(const bf16x8*)(wb0 + 2 * 64);                     \
        const bf16x8 b3 = *(const bf16x8*)(wb0 + 3 * 64);                     \
        acc[0] = __builtin_amdgcn_mfma_f32_16x16x32_bf16(a, b0, acc[0], 0, 0, 0); \
        acc[1] = __builtin_amdgcn_mfma_f32_16x16x32_bf16(a, b1, acc[1], 0, 0, 0); \
        acc[2] = __builtin_amdgcn_mfma_f32_16x16x32_bf16(a, b2, acc[2], 0, 0, 0); \
        acc[3] = __builtin_amdgcn_mfma_f32_16x16x32_bf16(a, b3, acc[3], 0, 0, 0); \
    }

    float4 w0A, w1A, c00A, c01A, c02A, c03A, c10A, c11A, c12A, c13A;
    float4 w0B, w1B, c00B, c01B, c02B, c03B, c10B, c11B, c12B, c13B;

    ISSUE(A, 0)
    ISSUE(B, 1) WRITE(A, 0)
    ISSUE(A, 2) WRITE(B, 1) DOMFMA(0)
    ISSUE(B, 3) WRITE(A, 2) DOMFMA(1)
    ISSUE(A, 4) WRITE(B, 3) DOMFMA(2)
    ISSUE(B, 5) WRITE(A, 4) DOMFMA(3)
    ISSUE(A, 6) WRITE(B, 5) DOMFMA(4)
    ISSUE(B, 7) WRITE(A, 6) DOMFMA(5)
    ISSUE(A, 8) WRITE(B, 7) DOMFMA(6)
                WRITE(A, 8) DOMFMA(7)
                            DOMFMA(8)

#undef ISSUE
#undef WRITE
#undef DOMFMA

    // ---- phase 4: pair reduction (red overlays dead ent area) ----
    __syncthreads();
    if (kw == 1) {
        #pragma unroll
        for (int nf = 0; nf < 4; ++nf) red[(pair * 4 + nf) * 64 + lane] = acc[nf];
    }
    __syncthreads();
    if (kw == 0) {
        #pragma unroll
        for (int nf = 0; nf < 4; ++nf) {
            const f32x4 o = red[(pair * 4 + nf) * 64 + lane];
            const int n  = nf * 16 + (lane & 15);
            const float bs = bias[n];
            const int m0 = pair * 16 + ((lane >> 4) * 4);
            #pragma unroll
            for (int r = 0; r < 4; ++r) {
                out[(size_t)(pix0 + m0 + r) * COUT + n] = acc[nf][r] + o[r] + bs;
            }
        }
    }
}

extern "C" void kernel_launch(void* const* d_in, const int* in_sizes, int n_in,
                              void* d_out, int out_size, void* d_ws, size_t ws_size,
                              hipStream_t stream)
{
    const float* x     = (const float*)d_in[0];
    const float* wmain = (const float*)d_in[1];
    const float* bias  = (const float*)d_in[2];
    const float* wofs  = (const float*)d_in[3];
    const float* bofs  = (const float*)d_in[4];
    float* out = (float*)d_out;
    uint4* wb  = (uint4*)d_ws;                          // 73728 B
    uint4* wf  = (uint4*)((char*)d_ws + 73728);         // 36864 B

    weight_transform<<<108, 64, 0, stream>>>(wmain, wofs, wb, wf);
    dcn_fused<<<NPIX / TMB, 256, 0, stream>>>(x, wb, wf, bias, bofs, out);
}

// Round 19
// 38.188 us; speedup vs baseline: 1.1814x; 1.1483x over previous
//
#include <hip/hip_runtime.h>
#include <hip/hip_bf16.h>
#include <math.h>

#define BB 4
#define HH 128
#define WW 128
#define CIN 64
#define COUT 64
#define KK 9
#define OMC 27
#define NPIX (BB * HH * WW)

typedef __attribute__((ext_vector_type(8))) short bf16x8;
typedef __attribute__((ext_vector_type(4))) float f32x4;

static __device__ __forceinline__ unsigned int pkcvt(float a, float b) {
    __hip_bfloat162 h = __float22bfloat162_rn(make_float2(a, b));
    return *reinterpret_cast<unsigned int*>(&h);
}
static __device__ __forceinline__ float bflo(unsigned int u) {
    return __uint_as_float(u << 16);
}
static __device__ __forceinline__ float bfhi(unsigned int u) {
    return __uint_as_float(u & 0xffff0000u);
}

// ---------------------------------------------------------------------------
// Kernel 0: one-shot weight transforms (unchanged).
// ---------------------------------------------------------------------------
__global__ __launch_bounds__(64) void weight_transform(
    const float* __restrict__ wmain, const float* __restrict__ wofs,
    uint4* __restrict__ wb, uint4* __restrict__ wf)
{
    const int tg = blockIdx.x * 64 + threadIdx.x;
    if (tg < 4608) {
        const int lane = tg & 63;
        const int nf   = (tg >> 6) & 3;
        const int ks   = tg >> 8;
        const int k0   = ks * 32 + ((lane >> 4) * 8);
        const int n    = nf * 16 + (lane & 15);
        uint4 q;
        q.x = pkcvt(wmain[(size_t)(k0 + 0) * COUT + n], wmain[(size_t)(k0 + 1) * COUT + n]);
        q.y = pkcvt(wmain[(size_t)(k0 + 2) * COUT + n], wmain[(size_t)(k0 + 3) * COUT + n]);
        q.z = pkcvt(wmain[(size_t)(k0 + 4) * COUT + n], wmain[(size_t)(k0 + 5) * COUT + n]);
        q.w = pkcvt(wmain[(size_t)(k0 + 6) * COUT + n], wmain[(size_t)(k0 + 7) * COUT + n]);
        wb[tg] = q;
    } else {
        const int idx  = tg - 4608;
        const int lane = idx & 63;
        const int frag = idx >> 6;
        const int nf   = frag & 1;
        const int ks   = frag >> 1;
        const int t    = ks >> 1;
        const int kw   = ks & 1;
        const int j    = nf * 16 + (lane & 15);
        const int c0   = kw * 32 + ((lane >> 4) * 8);
        uint4 q;
        if (j < OMC) {
            const float* wp = wofs + ((size_t)t * CIN + c0) * OMC + j;
            q.x = pkcvt(wp[0 * OMC], wp[1 * OMC]);
            q.y = pkcvt(wp[2 * OMC], wp[3 * OMC]);
            q.z = pkcvt(wp[4 * OMC], wp[5 * OMC]);
            q.w = pkcvt(wp[6 * OMC], wp[7 * OMC]);
        } else {
            q.x = q.y = q.z = q.w = 0u;
        }
        wf[frag * 64 + lane] = q;
    }
}

// ---------------------------------------------------------------------------
// FUSED kernel.  Key change vs R13-R18: phase 3 gathers bilinear corners
// FROM THE LDS x-TILE (5 rows x 36 cols halo, bf16, XOR-swizzled) instead
// of re-fetching ~600 MB from L2.  Each lane builds its MFMA A-fragment's
// own 8 channels directly in registers (pixel = lane&15, ch-group =
// lane>>4) -- no transpose tile, no ds_write/ds_read round-trip, no global
// gather pipeline.  Rare out-of-tile offsets (|d|>~1) fall back to the
// exact global-clamped path via a per-entry flag (correct for any data).
// LDS 36864 B: xs5 23040 (ph0-3) | om_s 3456 (ph1-2) | ent 10368 (ph2-3,
// om_red overlays ent_w in ph1; red overlays xs5 in ph4).
// 4 blocks/CU by LDS -> scheduler target 4 waves/EU = 128-VGPR budget.
// ---------------------------------------------------------------------------
#define TMB 32   // pixels per block

__global__ __launch_bounds__(256) void dcn_fused(
    const float* __restrict__ x,
    const uint4* __restrict__ wb,
    const uint4* __restrict__ wf,
    const float* __restrict__ bias,
    const float* __restrict__ bofs,
    float* __restrict__ out)
{
    __shared__ char shm[23040 + 3456 + 4608 + 4608 + 1152];  // 36864
    char*   xs5   = shm;                              // [0,23040)   ph0-3
    float*  om_s  = (float*)(shm + 23040);            // [23040,26496) ph1-2
    float4* ent_w = (float4*)(shm + 26496);           // ph2-3
    int4*   ent_o = (int4*)(shm + 31104);             // ph2-3
    int*    ent_f = (int*)(shm + 35712);              // ph2-3
    f32x4*  om_red = (f32x4*)(shm + 26496);           // ph1 reduce (pre-ent)
    f32x4*  red    = (f32x4*)shm;                     // ph4 (overlay xs5)

    const int tid  = threadIdx.x;
    const int lane = tid & 63;
    const int wv   = tid >> 6;
    const int pair = wv >> 1;
    const int kw   = wv & 1;
    const int bid  = ((blockIdx.x & 7) << 8) + (blockIdx.x >> 3);  // XCD chunk
    const int pix0 = bid * TMB;
    const int b    = pix0 >> 14;
    const int h    = (pix0 >> 7) & (HH - 1);
    const int w0   = pix0 & (WW - 1);
    const float* xb = x + (size_t)b * HH * WW * CIN;

    // ---- phase 0: stage x tile [5 rows][36 cols][64 ch] bf16, swizzled ----
    // cell = ty*36+wi (180 cells x 128B); global row h-2+ty, col w0-2+wi.
    #pragma unroll
    for (int it = 0; it < 6; ++it) {
        const int idx = it * 256 + tid;
        if (idx < 1440) {
            const int c8   = idx & 7;
            const int cell = idx >> 3;          // [0,180)
            const int ty   = cell / 36;
            const int wi   = cell - ty * 36;
            const int hy   = h - 2 + ty;
            const int wcol = w0 - 2 + wi;
            uint4 q;
            if ((unsigned)hy < (unsigned)HH && (unsigned)wcol < (unsigned)WW) {
                const float* p = xb + ((size_t)hy * WW + wcol) * CIN + c8 * 8;
                const float4 a0 = *(const float4*)p;
                const float4 a1 = *(const float4*)(p + 4);
                q.x = pkcvt(a0.x, a0.y);
                q.y = pkcvt(a0.z, a0.w);
                q.z = pkcvt(a1.x, a1.y);
                q.w = pkcvt(a1.z, a1.w);
            } else {
                q.x = q.y = q.z = q.w = 0u;
            }
            const int off = cell * 128 + ((c8 * 16) ^ ((cell & 7) << 4));
            *(uint4*)(xs5 + off) = q;
        }
    }
    __syncthreads();

    // ---- phase 1: om GEMM (A from xs5 rows 1..3) ----
    f32x4 accm[2] = {};
    #pragma unroll
    for (int t = 0; t < KK; ++t) {
        const int ty = t / 3, tx = t % 3;
        const int cell = (ty + 1) * 36 + (pair * 16 + (lane & 15) + tx + 1);
        const int aoff = cell * 128 + ((kw * 64 + (lane >> 4) * 16) ^ ((cell & 7) << 4));
        const bf16x8 a = *(const bf16x8*)(xs5 + aoff);
        const uint4* wf0 = wf + ((t * 2 + kw) * 2) * 64 + lane;
        const bf16x8 b0 = *(const bf16x8*)(wf0);
        const bf16x8 b1 = *(const bf16x8*)(wf0 + 64);
        accm[0] = __builtin_amdgcn_mfma_f32_16x16x32_bf16(a, b0, accm[0], 0, 0, 0);
        accm[1] = __builtin_amdgcn_mfma_f32_16x16x32_bf16(a, b1, accm[1], 0, 0, 0);
    }

    if (kw == 1) {
        om_red[(pair * 2 + 0) * 64 + lane] = accm[0];
        om_red[(pair * 2 + 1) * 64 + lane] = accm[1];
    }
    __syncthreads();
    if (kw == 0) {
        #pragma unroll
        for (int nf = 0; nf < 2; ++nf) {
            const int j = nf * 16 + (lane & 15);
            if (j >= OMC) continue;
            const f32x4 o = om_red[(pair * 2 + nf) * 64 + lane];
            const float bb = bofs[j];
            const int m0 = pair * 16 + ((lane >> 4) * 4);
            #pragma unroll
            for (int r = 0; r < 4; ++r) {
                float val = accm[nf][r] + o[r] + bb;
                const int wpix = w0 + m0 + r;
                if (j < 18) {
                    const int t = j >> 1;
                    if ((j & 1) == 0) val += (float)(h - 1 + t / 3);     // abs py
                    else              val += (float)(wpix - 1 + t % 3);  // abs px
                } else {
                    val = 1.0f / (1.0f + __expf(-val));                  // sigmoid
                }
                om_s[(m0 + r) * OMC + j] = val;
            }
        }
    }
    __syncthreads();

    // ---- phase 2: entry precompute (LDS offsets when in-tile, else global) ----
    for (int e = tid; e < 288; e += 256) {
        const int px = e / 9;
        const int t  = e - px * 9;
        const float py  = om_s[px * OMC + 2 * t];
        const float pxx = om_s[px * OMC + 2 * t + 1];
        const float mk  = om_s[px * OMC + 18 + t];

        const float fy = floorf(py), fx = floorf(pxx);
        const int y0 = (int)fy, x0 = (int)fx;
        const float wy1 = py - fy, wx1 = pxx - fx;
        const float wy0 = 1.0f - wy1, wx0 = 1.0f - wx1;
        const bool vy0 = (unsigned)y0 < (unsigned)HH;
        const bool vy1 = (unsigned)(y0 + 1) < (unsigned)HH;
        const bool vx0 = (unsigned)x0 < (unsigned)WW;
        const bool vx1 = (unsigned)(x0 + 1) < (unsigned)WW;
        float4 w4;
        w4.x = (vy0 && vx0) ? wy0 * wx0 * mk : 0.0f;
        w4.y = (vy0 && vx1) ? wy0 * wx1 * mk : 0.0f;
        w4.z = (vy1 && vx0) ? wy1 * wx0 * mk : 0.0f;
        w4.w = (vy1 && vx1) ? wy1 * wx1 * mk : 0.0f;

        const int r0  = y0 - (h - 2);
        const int c0i = x0 - (w0 - 2);
        int4 o4;
        int fl;
        if ((unsigned)r0 <= 3u && (unsigned)c0i <= 34u) {
            const int base = r0 * 36 + c0i;
            o4.x = base * 128;
            o4.y = (base + 1) * 128;
            o4.z = (base + 36) * 128;
            o4.w = (base + 37) * 128;
            fl = 0;
        } else {
            const int yc0 = min(max(y0, 0), HH - 1);
            const int yc1 = min(max(y0 + 1, 0), HH - 1);
            const int xc0 = min(max(x0, 0), WW - 1);
            const int xc1 = min(max(x0 + 1, 0), WW - 1);
            o4.x = (yc0 * WW + xc0) * (CIN * 4);
            o4.y = (yc0 * WW + xc1) * (CIN * 4);
            o4.z = (yc1 * WW + xc0) * (CIN * 4);
            o4.w = (yc1 * WW + xc1) * (CIN * 4);
            fl = 1;
        }
        ent_w[e] = w4;
        ent_o[e] = o4;
        ent_f[e] = fl;
    }
    __syncthreads();

    // ---- phase 3: LDS gather -> A-frag in regs -> MFMA ----
    const int p   = lane & 15;            // A-frag pixel row
    const int g   = lane >> 4;            // channel group (8 ch)
    const int kwg = kw * 64 + g * 16;     // byte offset of this lane's 16B
    const char* xg = (const char*)xb + (size_t)(kw * 32 + g * 8) * 4;
    const int ebase = pair * 144 + p * 9;

    f32x4 acc[4] = {};

    #pragma unroll
    for (int t = 0; t < KK; ++t) {
        const float4 w4 = ent_w[ebase + t];
        const int4   o4 = ent_o[ebase + t];
        float s[8];
        if (ent_f[ebase + t] == 0) {
            const uint4 q0 = *(const uint4*)(xs5 + o4.x + (kwg ^ ((o4.x >> 3) & 0x70)));
            const uint4 q1 = *(const uint4*)(xs5 + o4.y + (kwg ^ ((o4.y >> 3) & 0x70)));
            const uint4 q2 = *(const uint4*)(xs5 + o4.z + (kwg ^ ((o4.z >> 3) & 0x70)));
            const uint4 q3 = *(const uint4*)(xs5 + o4.w + (kwg ^ ((o4.w >> 3) & 0x70)));
            const unsigned int* u0 = (const unsigned int*)&q0;
            const unsigned int* u1 = (const unsigned int*)&q1;
            const unsigned int* u2 = (const unsigned int*)&q2;
            const unsigned int* u3 = (const unsigned int*)&q3;
            #pragma unroll
            for (int i = 0; i < 4; ++i) {
                s[2 * i]     = w4.x * bflo(u0[i]) + w4.y * bflo(u1[i])
                             + w4.z * bflo(u2[i]) + w4.w * bflo(u3[i]);
                s[2 * i + 1] = w4.x * bfhi(u0[i]) + w4.y * bfhi(u1[i])
                             + w4.z * bfhi(u2[i]) + w4.w * bfhi(u3[i]);
            }
        } else {
            const float4 c0a = *(const float4*)(xg + o4.x);
            const float4 c0b = *(const float4*)(xg + o4.x + 16);
            const float4 c1a = *(const float4*)(xg + o4.y);
            const float4 c1b = *(const float4*)(xg + o4.y + 16);
            const float4 c2a = *(const float4*)(xg + o4.z);
            const float4 c2b = *(const float4*)(xg + o4.z + 16);
            const float4 c3a = *(const float4*)(xg + o4.w);
            const float4 c3b = *(const float4*)(xg + o4.w + 16);
            #pragma unroll
            for (int i = 0; i < 4; ++i) {
                s[i]     = w4.x * ((const float*)&c0a)[i] + w4.y * ((const float*)&c1a)[i]
                         + w4.z * ((const float*)&c2a)[i] + w4.w * ((const float*)&c3a)[i];
                s[4 + i] = w4.x * ((const float*)&c0b)[i] + w4.y * ((const float*)&c1b)[i]
                         + w4.z * ((const float*)&c2b)[i] + w4.w * ((const float*)&c3b)[i];
            }
        }

        uint4 aq;
        aq.x = pkcvt(s[0], s[1]);
        aq.y = pkcvt(s[2], s[3]);
        aq.z = pkcvt(s[4], s[5]);
        aq.w = pkcvt(s[6], s[7]);
        const bf16x8 a = *(const bf16x8*)&aq;

        const uint4* wb0 = wb + ((t * 2 + kw) * 4) * 64 + lane;
        const bf16x8 b0 = *(const bf16x8*)(wb0 + 0 * 64);
        const bf16x8 b1 = *(const bf16x8*)(wb0 + 1 * 64);
        const bf16x8 b2 = *(const bf16x8*)(wb0 + 2 * 64);
        const bf16x8 b3 = *(const bf16x8*)(wb0 + 3 * 64);
        acc[0] = __builtin_amdgcn_mfma_f32_16x16x32_bf16(a, b0, acc[0], 0, 0, 0);
        acc[1] = __builtin_amdgcn_mfma_f32_16x16x32_bf16(a, b1, acc[1], 0, 0, 0);
        acc[2] = __builtin_amdgcn_mfma_f32_16x16x32_bf16(a, b2, acc[2], 0, 0, 0);
        acc[3] = __builtin_amdgcn_mfma_f32_16x16x32_bf16(a, b3, acc[3], 0, 0, 0);
    }

    // ---- phase 4: pair reduction (red overlays dead xs5) ----
    __syncthreads();
    if (kw == 1) {
        #pragma unroll
        for (int nf = 0; nf < 4; ++nf) red[(pair * 4 + nf) * 64 + lane] = acc[nf];
    }
    __syncthreads();
    if (kw == 0) {
        #pragma unroll
        for (int nf = 0; nf < 4; ++nf) {
            const f32x4 o = red[(pair * 4 + nf) * 64 + lane];
            const int n  = nf * 16 + (lane & 15);
            const float bs = bias[n];
            const int m0 = pair * 16 + ((lane >> 4) * 4);
            #pragma unroll
            for (int r = 0; r < 4; ++r) {
                out[(size_t)(pix0 + m0 + r) * COUT + n] = acc[nf][r] + o[r] + bs;
            }
        }
    }
}

extern "C" void kernel_launch(void* const* d_in, const int* in_sizes, int n_in,
                              void* d_out, int out_size, void* d_ws, size_t ws_size,
                              hipStream_t stream)
{
    const float* x     = (const float*)d_in[0];
    const float* wmain = (const float*)d_in[1];
    const float* bias  = (const float*)d_in[2];
    const float* wofs  = (const float*)d_in[3];
    const float* bofs  = (const float*)d_in[4];
    float* out = (float*)d_out;
    uint4* wb  = (uint4*)d_ws;                          // 73728 B
    uint4* wf  = (uint4*)((char*)d_ws + 73728);         // 36864 B

    weight_transform<<<108, 64, 0, stream>>>(wmain, wofs, wb, wf);
    dcn_fused<<<NPIX / TMB, 256, 0, stream>>>(x, wb, wf, bias, bofs, out);
}